// Round 1
// baseline (319.116 us; speedup 1.0000x reference)
//
#include <hip/hip_runtime.h>
#include <hip/hip_bf16.h>
#include <math.h>

// Problem constants (match reference)
#define BB 8
#define NN 2048
#define C_IN 64
#define NCH 64
#define NTERMS 3
#define LN_EPS 1e-5f

// ---------------------------------------------------------------------------
// Kernel 1: Xs[b,n] = sum_c X[b,n,c].  C_IN == 64 == wave size: one lane per
// channel, butterfly shuffle reduce.  4 waves / block -> 4 rows / block.
// ---------------------------------------------------------------------------
__global__ void xsum_kernel(const float* __restrict__ X, float* __restrict__ Xs) {
    int row  = (blockIdx.x * blockDim.x + threadIdx.x) >> 6;   // b*NN + n
    int lane = threadIdx.x & 63;
    float v = X[(size_t)row * C_IN + lane];
    #pragma unroll
    for (int off = 32; off > 0; off >>= 1)
        v += __shfl_down(v, off, 64);
    if (lane == 0) Xs[row] = v;
}

// ---------------------------------------------------------------------------
// Kernel 2: batched matvec  pout[b,m] = sum_n A[b,m,n] * pin[b,n]
// grid = (NN/ROWS, BB), block = 256 (4 waves).  p[b,:] staged in LDS.
// Each wave processes rows m0+wave, m0+wave+4, ... ; per row: 8 float4
// global loads (2048 floats / 64 lanes) + float4 LDS reads, then 64-lane
// butterfly reduction.
// ---------------------------------------------------------------------------
#define MV_ROWS 16
__global__ __launch_bounds__(256) void matvec_kernel(
        const float* __restrict__ A,
        const float* __restrict__ pin,
        float* __restrict__ pout) {
    __shared__ float p[NN];
    const int b  = blockIdx.y;
    const int m0 = blockIdx.x * MV_ROWS;

    // stage pin[b,:] into LDS (coalesced float4)
    const float4* pin4 = (const float4*)(pin + (size_t)b * NN);
    float4* p4 = (float4*)p;
    for (int i = threadIdx.x; i < NN / 4; i += blockDim.x)
        p4[i] = pin4[i];
    __syncthreads();

    const int wave = threadIdx.x >> 6;
    const int lane = threadIdx.x & 63;
    const float* Ab = A + (size_t)b * NN * NN;

    for (int r = wave; r < MV_ROWS; r += 4) {
        const int m = m0 + r;
        const float4* Arow = (const float4*)(Ab + (size_t)m * NN);
        float acc = 0.f;
        #pragma unroll
        for (int it = 0; it < NN / 4 / 64; ++it) {   // 8 iterations
            float4 a  = Arow[it * 64 + lane];
            float4 pv = p4[it * 64 + lane];
            acc += a.x * pv.x + a.y * pv.y + a.z * pv.z + a.w * pv.w;
        }
        #pragma unroll
        for (int off = 32; off > 0; off >>= 1)
            acc += __shfl_down(acc, off, 64);
        if (lane == 0) pout[(size_t)b * NN + m] = acc;
    }
}

// ---------------------------------------------------------------------------
// Kernel 3: one thread per (b,n).
//   Y[c] = sum_i h[i,c,n] * P[i,b,n];  LayerNorm over c; tanh; store.
// h loads are coalesced across lanes (consecutive n -> consecutive addresses).
// ---------------------------------------------------------------------------
__global__ __launch_bounds__(256) void combine_kernel(
        const float* __restrict__ h,      // [4, 64, NN]
        const float* __restrict__ P,      // [4, BB, NN]
        const float* __restrict__ gamma,  // [64]
        const float* __restrict__ beta,   // [64]
        float* __restrict__ out) {        // [BB, NN, 64]
    const int idx = blockIdx.x * blockDim.x + threadIdx.x;  // b*NN + n
    const int n   = idx & (NN - 1);

    const float p0 = P[0 * BB * NN + idx];
    const float p1 = P[1 * BB * NN + idx];
    const float p2 = P[2 * BB * NN + idx];
    const float p3 = P[3 * BB * NN + idx];

    float y[NCH];
    float s = 0.f;
    #pragma unroll
    for (int c = 0; c < NCH; ++c) {
        float v = h[(size_t)(0 * NCH + c) * NN + n] * p0
                + h[(size_t)(1 * NCH + c) * NN + n] * p1
                + h[(size_t)(2 * NCH + c) * NN + n] * p2
                + h[(size_t)(3 * NCH + c) * NN + n] * p3;
        y[c] = v;
        s += v;
    }
    const float mean = s * (1.f / NCH);
    float vs = 0.f;
    #pragma unroll
    for (int c = 0; c < NCH; ++c) {
        float d = y[c] - mean;
        vs += d * d;
    }
    const float rstd = rsqrtf(vs * (1.f / NCH) + LN_EPS);

    float4* out4 = (float4*)(out + (size_t)idx * NCH);
    #pragma unroll
    for (int c4 = 0; c4 < NCH / 4; ++c4) {
        float4 o;
        o.x = tanhf((y[4 * c4 + 0] - mean) * rstd * gamma[4 * c4 + 0] + beta[4 * c4 + 0]);
        o.y = tanhf((y[4 * c4 + 1] - mean) * rstd * gamma[4 * c4 + 1] + beta[4 * c4 + 1]);
        o.z = tanhf((y[4 * c4 + 2] - mean) * rstd * gamma[4 * c4 + 2] + beta[4 * c4 + 2]);
        o.w = tanhf((y[4 * c4 + 3] - mean) * rstd * gamma[4 * c4 + 3] + beta[4 * c4 + 3]);
        out4[c4] = o;
    }
}

// ---------------------------------------------------------------------------
extern "C" void kernel_launch(void* const* d_in, const int* in_sizes, int n_in,
                              void* d_out, int out_size, void* d_ws, size_t ws_size,
                              hipStream_t stream) {
    const float* A     = (const float*)d_in[0];  // [B, N, N]
    const float* X     = (const float*)d_in[1];  // [B, N, C_IN]
    const float* h     = (const float*)d_in[2];  // [4, 64, N]
    const float* gamma = (const float*)d_in[3];  // [64]
    const float* beta  = (const float*)d_in[4];  // [64]
    float* out = (float*)d_out;                  // [B, N, 64]

    // workspace: P[4][B][N] floats = 256 KB
    float* P = (float*)d_ws;

    // 1) P[0] = Xs = rowsum(X)
    {
        int rows = BB * NN;                 // 16384 rows, 4 rows/block
        xsum_kernel<<<rows / 4, 256, 0, stream>>>(X, P);
    }

    // 2) P[i] = A @ P[i-1], i = 1..3  (sequential dependency)
    dim3 mv_grid(NN / MV_ROWS, BB);
    for (int i = 1; i <= NTERMS; ++i) {
        matvec_kernel<<<mv_grid, 256, 0, stream>>>(
            A, P + (size_t)(i - 1) * BB * NN, P + (size_t)i * BB * NN);
    }

    // 3) combine + LayerNorm + tanh
    combine_kernel<<<(BB * NN) / 256, 256, 0, stream>>>(h, P, gamma, beta, out);
}

// Round 2
// 262.841 us; speedup vs baseline: 1.2141x; 1.2141x over previous
//
#include <hip/hip_runtime.h>
#include <hip/hip_bf16.h>
#include <math.h>

// Problem constants (match reference)
#define BB 8
#define NN 2048
#define C_IN 64
#define NCH 64
#define NTERMS 3
#define LN_EPS 1e-5f

// ---------------------------------------------------------------------------
// Kernel 1: Xs[b,n] = sum_c X[b,n,c].  C_IN == 64 == wave size: one lane per
// channel, butterfly shuffle reduce.  4 waves / block -> 4 rows / block.
// ---------------------------------------------------------------------------
__global__ void xsum_kernel(const float* __restrict__ X, float* __restrict__ Xs) {
    int row  = (blockIdx.x * blockDim.x + threadIdx.x) >> 6;   // b*NN + n
    int lane = threadIdx.x & 63;
    float v = X[(size_t)row * C_IN + lane];
    #pragma unroll
    for (int off = 32; off > 0; off >>= 1)
        v += __shfl_down(v, off, 64);
    if (lane == 0) Xs[row] = v;
}

// ---------------------------------------------------------------------------
// Kernel 2: batched matvec  pout[b,m] = sum_n A[b,m,n] * pin[b,n]
// grid = (NN/MV_ROWS, BB), block = 256 (4 waves).  p[b,:] staged in LDS.
// Each wave owns 4 CONSECUTIVE rows processed CONCURRENTLY: 32 independent
// float4 global loads in flight, LDS vector read once and reused for all 4
// rows, 4 butterfly reductions at the end, one float4 store.
// ---------------------------------------------------------------------------
#define MV_ROWS 16   // rows per block = 4 waves * 4 rows
__global__ __launch_bounds__(256) void matvec_kernel(
        const float* __restrict__ A,
        const float* __restrict__ pin,
        float* __restrict__ pout) {
    __shared__ float p[NN];
    const int b  = blockIdx.y;
    const int m0 = blockIdx.x * MV_ROWS;

    // stage pin[b,:] into LDS (coalesced float4)
    const float4* pin4 = (const float4*)(pin + (size_t)b * NN);
    float4* p4 = (float4*)p;
    for (int i = threadIdx.x; i < NN / 4; i += blockDim.x)
        p4[i] = pin4[i];
    __syncthreads();

    const int wave = threadIdx.x >> 6;
    const int lane = threadIdx.x & 63;
    const float* Ab = A + (size_t)b * NN * NN;

    const int m = m0 + wave * 4;   // this wave's 4 rows
    const float4* r0 = (const float4*)(Ab + (size_t)(m + 0) * NN);
    const float4* r1 = (const float4*)(Ab + (size_t)(m + 1) * NN);
    const float4* r2 = (const float4*)(Ab + (size_t)(m + 2) * NN);
    const float4* r3 = (const float4*)(Ab + (size_t)(m + 3) * NN);

    float a0 = 0.f, a1 = 0.f, a2 = 0.f, a3 = 0.f;
    #pragma unroll
    for (int it = 0; it < NN / 4 / 64; ++it) {   // 8 iterations
        const int o = it * 64 + lane;
        float4 pv = p4[o];
        float4 x0 = r0[o];
        float4 x1 = r1[o];
        float4 x2 = r2[o];
        float4 x3 = r3[o];
        a0 += x0.x * pv.x + x0.y * pv.y + x0.z * pv.z + x0.w * pv.w;
        a1 += x1.x * pv.x + x1.y * pv.y + x1.z * pv.z + x1.w * pv.w;
        a2 += x2.x * pv.x + x2.y * pv.y + x2.z * pv.z + x2.w * pv.w;
        a3 += x3.x * pv.x + x3.y * pv.y + x3.z * pv.z + x3.w * pv.w;
    }
    #pragma unroll
    for (int off = 32; off > 0; off >>= 1) {
        a0 += __shfl_down(a0, off, 64);
        a1 += __shfl_down(a1, off, 64);
        a2 += __shfl_down(a2, off, 64);
        a3 += __shfl_down(a3, off, 64);
    }
    if (lane == 0) {
        float4 o4 = make_float4(a0, a1, a2, a3);
        *(float4*)(pout + (size_t)b * NN + m) = o4;
    }
}

// ---------------------------------------------------------------------------
// Kernel 3: one WAVE per (b,n); lane = channel.
//   y = sum_i h[i,lane,n] * P[i,b,n];  LayerNorm across the wave; tanh; store.
// No per-thread arrays (no spill); butterfly all-reduce for mean/var;
// coalesced 64-float store per wave.  16384 waves -> full occupancy.
// ---------------------------------------------------------------------------
__global__ __launch_bounds__(256) void combine_kernel(
        const float* __restrict__ h,      // [4, 64, NN]
        const float* __restrict__ P,      // [4, BB, NN]
        const float* __restrict__ gamma,  // [64]
        const float* __restrict__ beta,   // [64]
        float* __restrict__ out) {        // [BB, NN, 64]
    const int idx  = (blockIdx.x * blockDim.x + threadIdx.x) >> 6;  // b*NN + n
    const int lane = threadIdx.x & 63;                              // channel
    const int n    = idx & (NN - 1);

    const float p0 = P[0 * BB * NN + idx];
    const float p1 = P[1 * BB * NN + idx];
    const float p2 = P[2 * BB * NN + idx];
    const float p3 = P[3 * BB * NN + idx];

    float y = h[(size_t)(0 * NCH + lane) * NN + n] * p0
            + h[(size_t)(1 * NCH + lane) * NN + n] * p1
            + h[(size_t)(2 * NCH + lane) * NN + n] * p2
            + h[(size_t)(3 * NCH + lane) * NN + n] * p3;

    // mean (all-lanes butterfly)
    float s = y;
    #pragma unroll
    for (int off = 32; off > 0; off >>= 1)
        s += __shfl_xor(s, off, 64);
    const float mean = s * (1.f / NCH);

    float d = y - mean;
    float vs = d * d;
    #pragma unroll
    for (int off = 32; off > 0; off >>= 1)
        vs += __shfl_xor(vs, off, 64);
    const float rstd = rsqrtf(vs * (1.f / NCH) + LN_EPS);

    out[(size_t)idx * NCH + lane] = tanhf(d * rstd * gamma[lane] + beta[lane]);
}

// ---------------------------------------------------------------------------
extern "C" void kernel_launch(void* const* d_in, const int* in_sizes, int n_in,
                              void* d_out, int out_size, void* d_ws, size_t ws_size,
                              hipStream_t stream) {
    const float* A     = (const float*)d_in[0];  // [B, N, N]
    const float* X     = (const float*)d_in[1];  // [B, N, C_IN]
    const float* h     = (const float*)d_in[2];  // [4, 64, N]
    const float* gamma = (const float*)d_in[3];  // [64]
    const float* beta  = (const float*)d_in[4];  // [64]
    float* out = (float*)d_out;                  // [B, N, 64]

    // workspace: P[4][B][N] floats = 256 KB
    float* P = (float*)d_ws;

    // 1) P[0] = Xs = rowsum(X)
    {
        int rows = BB * NN;                 // 16384 rows, 4 rows/block
        xsum_kernel<<<rows / 4, 256, 0, stream>>>(X, P);
    }

    // 2) P[i] = A @ P[i-1], i = 1..3  (sequential dependency)
    dim3 mv_grid(NN / MV_ROWS, BB);
    for (int i = 1; i <= NTERMS; ++i) {
        matvec_kernel<<<mv_grid, 256, 0, stream>>>(
            A, P + (size_t)(i - 1) * BB * NN, P + (size_t)i * BB * NN);
    }

    // 3) combine + LayerNorm + tanh  (wave per (b,n): 16384 waves)
    combine_kernel<<<(BB * NN * 64) / 256, 256, 0, stream>>>(h, P, gamma, beta, out);
}